// Round 2
// baseline (340.390 us; speedup 1.0000x reference)
//
#include <hip/hip_runtime.h>

#define LEAKY 0.2f

typedef __attribute__((ext_vector_type(8))) short short8;   // 8 bf16 (MFMA A/B frag)
typedef __attribute__((ext_vector_type(4))) float floatx4;  // MFMA C/D frag
typedef __attribute__((ext_vector_type(8))) unsigned short ushort8_t;

__device__ __forceinline__ float bf2f(unsigned short u) {
    return __uint_as_float(((unsigned)u) << 16);
}
__device__ __forceinline__ unsigned short f2bf(float f) {
    unsigned u = __float_as_uint(f);
    unsigned r = (u + 0x7fffu + ((u >> 16) & 1u)) >> 16;  // RNE
    return (unsigned short)r;
}
__device__ __forceinline__ float relu_nan(float v) { return v < 0.0f ? 0.0f : v; }

// async global->LDS, 16 B per lane (dest = wave-uniform base + lane*16)
__device__ __forceinline__ void gload_lds16(const void* g, void* l) {
    __builtin_amdgcn_global_load_lds((const __attribute__((address_space(1))) void*)g,
                                     (__attribute__((address_space(3))) void*)l, 16, 0, 0);
}

// ---------- K_fill (ws-too-small diagnosis: out filled with ws MB) ----------
__global__ void k_fill(float* __restrict__ p, float val, int n) {
    int i = blockIdx.x * blockDim.x + threadIdx.x;
    if (i < n) p[i] = val;
}

// ---------- K_prep: cvt X, weight transposes, score-weight matvec, edge histogram ----------
// cnt must be zeroed (hipMemsetAsync) before this kernel.
__global__ void k_prep(const float* __restrict__ X, unsigned short* __restrict__ Xb,
                       const float* __restrict__ Wn, unsigned short* __restrict__ WnT,
                       const float* __restrict__ W1, unsigned short* __restrict__ W1T,
                       const float* __restrict__ W2, unsigned short* __restrict__ W2T,
                       const float* __restrict__ Asrc, const float* __restrict__ Adst,
                       float* __restrict__ Wsd,
                       const int* __restrict__ dst, int* __restrict__ cnt,
                       int N, int E) {
    const int gs = gridDim.x * blockDim.x;
    const int tid = blockIdx.x * blockDim.x + threadIdx.x;
    for (int i = tid; i < N * 32; i += gs) {
        float4 v = ((const float4*)X)[i];
        ushort4 o;
        o.x = f2bf(v.x); o.y = f2bf(v.y); o.z = f2bf(v.z); o.w = f2bf(v.w);
        ((ushort4*)Xb)[i] = o;
    }
    for (int i = tid; i < 256 * 128; i += gs) {   // WnT[col][k], col=head*64+d (per-head 64x128 blocks)
        int col = i >> 7, k = i & 127;
        int head = col >> 6, d = col & 63;
        WnT[i] = f2bf(Wn[(size_t)head * 8192 + (size_t)k * 64 + d]);
    }
    for (int i = tid; i < 256 * 256; i += gs) {   // W1T[n][k] = W1[k][n]
        int n = i >> 8, k = i & 255;
        W1T[i] = f2bf(W1[(size_t)k * 256 + n]);
    }
    for (int i = tid; i < 128 * 256; i += gs) {   // W2T[n][k] = W2[k][n]
        int n = i >> 8, k = i & 255;
        W2T[i] = f2bf(W2[(size_t)k * 128 + n]);
    }
    // Wsd[j][k]: j<4 -> Wn[h]@a_src[h], j>=4 -> Wn[h]@a_dst[h]  (h=j&3)
    for (int i = tid; i < 8 * 128; i += gs) {
        int j = i >> 7, k = i & 127, h = j & 3;
        const float* av = (j < 4 ? Asrc : Adst) + h * 64;
        const float* wrow = Wn + (size_t)h * 8192 + (size_t)k * 64;
        float acc = 0.0f;
        for (int d = 0; d < 64; ++d) acc += wrow[d] * av[d];
        Wsd[i] = acc;
    }
    for (int i = tid; i < E; i += gs) atomicAdd(cnt + dst[i], 1);  // fused histogram
}

// ---------- K_scores: s_src/s_dst = Xb @ Wsd^T  (per-node matvec, [N,8]) ----------
__global__ __launch_bounds__(256) void k_scores(
    const unsigned short* __restrict__ Xb, const float* __restrict__ Wsd,
    float* __restrict__ s_src, float* __restrict__ s_dst, int N) {
    const int gs = gridDim.x * 256;
    const int tid = blockIdx.x * 256 + threadIdx.x;
    for (int i = tid; i < N * 8; i += gs) {
        const int n = i >> 3, j = i & 7;
        const unsigned short* xr = Xb + (size_t)n * 128;
        const float* wr = Wsd + j * 128;
        float acc = 0.0f;
        for (int k = 0; k < 128; k += 8) {
            ushort8_t xv = *(const ushort8_t*)(xr + k);
#pragma unroll
            for (int u = 0; u < 8; ++u) acc = fmaf(bf2f(xv[u]), wr[k + u], acc);
        }
        if (j < 4) s_src[n * 4 + j] = acc;
        else       s_dst[n * 4 + (j - 4)] = acc;
    }
}

// ---------- K3a/b/c: two-level exclusive scan (proven version) ----------
__global__ __launch_bounds__(256) void k_scan1(
    const int* __restrict__ cnt, int* __restrict__ rowptr, int* __restrict__ bsum, int N) {
    __shared__ int wtot[4];
    const int lane = threadIdx.x & 63, wave = threadIdx.x >> 6;
    const int i = blockIdx.x * 256 + threadIdx.x;
    int v = (i < N) ? cnt[i] : 0;
    int x = v;
    for (int off = 1; off < 64; off <<= 1) {
        int y = __shfl_up(x, off, 64);
        if (lane >= off) x += y;
    }
    if (lane == 63) wtot[wave] = x;
    __syncthreads();
    int wo = 0;
    for (int wv = 0; wv < wave; ++wv) wo += wtot[wv];
    if (i < N) rowptr[i] = wo + x - v;
    if (threadIdx.x == 255) bsum[blockIdx.x] = wo + x;
}
__global__ void k_scan2(int* __restrict__ bsum, int nb) {
    const int lane = threadIdx.x;
    int carry = 0;
    for (int base = 0; base < nb; base += 64) {
        int i = base + lane;
        int v = (i < nb) ? bsum[i] : 0;
        int x = v;
        for (int off = 1; off < 64; off <<= 1) {
            int y = __shfl_up(x, off, 64);
            if (lane >= off) x += y;
        }
        if (i < nb) bsum[i] = carry + x - v;
        carry += __shfl(x, 63, 64);
    }
}
__global__ void k_scan3(int* __restrict__ rowptr, const int* __restrict__ bsum,
                        int* __restrict__ wcnt, int N, int E) {
    int i = blockIdx.x * blockDim.x + threadIdx.x;
    if (i < N) {
        int v = rowptr[i] + bsum[i >> 8];
        rowptr[i] = v;
        wcnt[i] = v;
    }
    if (i == N) rowptr[N] = E;
}

// ---------- K_scatter: src ids into CSR order + per-edge ex (4 heads, f32) ----------
__global__ void k_scatter(const int* __restrict__ src, const int* __restrict__ dst,
                          int* __restrict__ wcnt,
                          const float* __restrict__ s_src, const float* __restrict__ s_dst,
                          int* __restrict__ esrc, float* __restrict__ ex4, int E) {
    int e = blockIdx.x * blockDim.x + threadIdx.x;
    if (e < E) {
        const int s = src[e], d = dst[e];
        const int pos = atomicAdd(wcnt + d, 1);
        esrc[pos] = s;
        const float4 ss = *(const float4*)(s_src + (size_t)s * 4);
        const float4 sd = *(const float4*)(s_dst + (size_t)d * 4);
        float4 o;
        float v;
        v = ss.x + sd.x; v = fmaxf(v, LEAKY * v); o.x = __expf(v);
        v = ss.y + sd.y; v = fmaxf(v, LEAKY * v); o.y = __expf(v);
        v = ss.z + sd.z; v = fmaxf(v, LEAKY * v); o.z = __expf(v);
        v = ss.w + sd.w; v = fmaxf(v, LEAKY * v); o.w = __expf(v);
        *(float4*)(ex4 + (size_t)pos * 4) = o;
    }
}

// ---------- K_agg: X-space gather-aggregate -> agg[N][4][128] bf16 + invden[N][4] ----------
// One dst row per wave. Per edge: 1 gather of the 256 B X row (4 head-groups read
// the same addresses -> coalesced/merged), FMA into per-head 128-dim accumulators.
// esrc/ex loads for the next 16-edge block are software-pipelined over current FMAs.
__global__ __launch_bounds__(256) void k_agg(
    const unsigned short* __restrict__ Xb,
    const int* __restrict__ rowptr, const int* __restrict__ esrc,
    const float* __restrict__ ex4,
    unsigned short* __restrict__ agg, float* __restrict__ invden, int N) {
    const int lane = threadIdx.x & 63;
    const int wave = threadIdx.x >> 6;
    const int n = blockIdx.x * 4 + wave;
    if (n >= N) return;

    const int slot = lane & 15;       // edge slot within a 16-block
    const int g16  = lane & 48;       // head-group base lane
    const int head = lane >> 4;       // this lane's head
    const unsigned short* xcol = Xb + slot * 8;   // this lane's 8-dim slice

    const int beg = rowptr[n], end = rowptr[n + 1];

    float num[8] = {0, 0, 0, 0, 0, 0, 0, 0};
    float den = 0.0f;

    int base = beg;
    int sidv = 0; float exv = 0.0f;
    if (base < end) {
        const int rem = end - base;
        if (slot < rem) {
            sidv = esrc[base + slot];
            exv  = ex4[(size_t)(base + slot) * 4 + head];
        }
    }

    while (base < end) {
        const int rem = end - base;   // wave-uniform
        const int nb  = base + 16;
        int sidn = 0; float exn = 0.0f;
        if (nb < end) {
            const int rem2 = end - nb;
            if (slot < rem2) {
                sidn = esrc[nb + slot];
                exn  = ex4[(size_t)(nb + slot) * 4 + head];
            }
        }
        den += exv;

        if (rem >= 16) {
#pragma unroll
            for (int e = 0; e < 16; ++e) {
                const int s_   = __shfl(sidv, e, 64);
                const float x_ = __shfl(exv, g16 | e, 64);
                const ushort8_t xv = *(const ushort8_t*)(xcol + (size_t)s_ * 128);
#pragma unroll
                for (int j = 0; j < 8; ++j) num[j] = fmaf(x_, bf2f(xv[j]), num[j]);
            }
        } else {
            for (int e = 0; e < rem; ++e) {
                const int s_   = __shfl(sidv, e, 64);
                const float x_ = __shfl(exv, g16 | e, 64);
                const ushort8_t xv = *(const ushort8_t*)(xcol + (size_t)s_ * 128);
#pragma unroll
                for (int j = 0; j < 8; ++j) num[j] = fmaf(x_, bf2f(xv[j]), num[j]);
            }
        }
        sidv = sidn; exv = exn; base = nb;
    }

    // reduce den over the 16 slots within each head group (butterfly keeps group)
#pragma unroll
    for (int m = 1; m < 16; m <<= 1) den += __shfl_xor(den, m, 64);
    const float inv = 1.0f / (den > 0.0f ? den : 1.0f);

    ushort8_t o;
#pragma unroll
    for (int j = 0; j < 8; ++j) o[j] = f2bf(num[j]);   // relu applied after Wn transform
    *(ushort8_t*)(agg + (size_t)n * 512 + head * 128 + slot * 8) = o;
    if (slot == 0) invden[n * 4 + head] = inv;
}

// ---------- K_gemmh: per-head transform concat[n, h*64+d] = relu((agg[n,h,:]@Wn[h])*invden) ----------
// Block: 256 threads = 4 waves, tile 256 rows x 64 cols, K=128. grid=(N/256, 4 heads)
__global__ __launch_bounds__(256) void k_gemmh(
    const unsigned short* __restrict__ agg, const unsigned short* __restrict__ WnT,
    const float* __restrict__ invden, unsigned short* __restrict__ concat, int N) {
    __shared__ unsigned short As[256 * 32];
    __shared__ unsigned short Bs[64 * 32];
    const int t = threadIdx.x;
    const int lane = t & 63;
    const int w = t >> 6;
    const int lm = lane & 15, quad = lane >> 4;
    const int row0 = blockIdx.x * 256;
    const int head = blockIdx.y;

    floatx4 acc[4][4];
#pragma unroll
    for (int mi = 0; mi < 4; ++mi)
#pragma unroll
        for (int ni = 0; ni < 4; ++ni) acc[mi][ni] = (floatx4){0, 0, 0, 0};

    for (int k0 = 0; k0 < 128; k0 += 32) {
#pragma unroll
        for (int p = 0; p < 4; ++p) {
            int tr = p * 64 + (t >> 2);
            int ga = row0 + tr; if (ga >= N) ga = N - 1;   // clamp (stores guarded)
            gload_lds16(agg + (size_t)ga * 512 + head * 128 + k0 + (t & 3) * 8,
                        (char*)As + (size_t)tr * 64 + (t & 3) * 16);
        }
        {
            int tr = t >> 2;
            gload_lds16(WnT + (size_t)(head * 64 + tr) * 128 + k0 + (t & 3) * 8,
                        (char*)Bs + (size_t)tr * 64 + (t & 3) * 16);
        }
        __syncthreads();
        short8 af[4], bfr[4];
#pragma unroll
        for (int mi = 0; mi < 4; ++mi)
            af[mi] = *(const short8*)(As + (size_t)(w * 64 + mi * 16 + lm) * 32 + quad * 8);
#pragma unroll
        for (int ni = 0; ni < 4; ++ni)
            bfr[ni] = *(const short8*)(Bs + (size_t)(ni * 16 + lm) * 32 + quad * 8);
#pragma unroll
        for (int mi = 0; mi < 4; ++mi)
#pragma unroll
            for (int ni = 0; ni < 4; ++ni)
                acc[mi][ni] = __builtin_amdgcn_mfma_f32_16x16x32_bf16(af[mi], bfr[ni], acc[mi][ni], 0, 0, 0);
        __syncthreads();
    }

#pragma unroll
    for (int mi = 0; mi < 4; ++mi)
#pragma unroll
        for (int q = 0; q < 4; ++q) {
            const int r = row0 + w * 64 + mi * 16 + quad * 4 + q;
            if (r < N) {
                const float inv = invden[(size_t)r * 4 + head];
#pragma unroll
                for (int ni = 0; ni < 4; ++ni) {
                    const int c = ni * 16 + lm;
                    concat[(size_t)r * 256 + head * 64 + c] = f2bf(relu_nan(acc[mi][ni][q] * inv));
                }
            }
        }
}

// ---------- K_gemm: tiled MFMA GEMM (MLP layers) ----------
// MODE 1: bf16 out, +bias, relu     (MLP layer 1 -> hidden)
// MODE 2: fp32 out, +bias           (MLP layer 2 -> final)
template <int K, int MODE>
__global__ __launch_bounds__(256) void k_gemm(
    const unsigned short* __restrict__ A, const unsigned short* __restrict__ BT,
    const float* __restrict__ bias, unsigned short* __restrict__ Cb,
    float* __restrict__ Cf, int N, int ldout) {
    __shared__ unsigned short As[128 * 32];
    __shared__ unsigned short Bs[128 * 32];
    const int t = threadIdx.x;
    const int lane = t & 63;
    const int w = t >> 6;
    const int wy = w >> 1, wx = w & 1;
    const int lm = lane & 15, quad = lane >> 4;
    const int row0 = blockIdx.x * 128;
    const int n0 = blockIdx.y * 128;
    const int srow = lane >> 2;
    const int sk = (lane & 3) * 8;

    floatx4 acc[4][4];
#pragma unroll
    for (int ni = 0; ni < 4; ++ni) {
        float b = bias[n0 + wx * 64 + ni * 16 + lm];
#pragma unroll
        for (int mi = 0; mi < 4; ++mi) acc[mi][ni] = (floatx4){b, b, b, b};
    }

    for (int k0 = 0; k0 < K; k0 += 32) {
#pragma unroll
        for (int p = 0; p < 2; ++p) {
            int tr = (p * 4 + w) * 16 + srow;
            int ga = row0 + tr; if (ga >= N) ga = N - 1;   // clamp (stores guarded)
            gload_lds16(A + (size_t)ga * K + k0 + sk,
                        (char*)As + (size_t)tr * 64 + sk * 2);
            gload_lds16(BT + (size_t)(n0 + tr) * K + k0 + sk,
                        (char*)Bs + (size_t)tr * 64 + sk * 2);
        }
        __syncthreads();
        short8 af[4], bfr[4];
#pragma unroll
        for (int mi = 0; mi < 4; ++mi)
            af[mi] = *(const short8*)(As + (size_t)(wy * 64 + mi * 16 + lm) * 32 + quad * 8);
#pragma unroll
        for (int ni = 0; ni < 4; ++ni)
            bfr[ni] = *(const short8*)(Bs + (size_t)(wx * 64 + ni * 16 + lm) * 32 + quad * 8);
#pragma unroll
        for (int mi = 0; mi < 4; ++mi)
#pragma unroll
            for (int ni = 0; ni < 4; ++ni)
                acc[mi][ni] = __builtin_amdgcn_mfma_f32_16x16x32_bf16(af[mi], bfr[ni], acc[mi][ni], 0, 0, 0);
        __syncthreads();
    }

#pragma unroll
    for (int mi = 0; mi < 4; ++mi)
#pragma unroll
        for (int ni = 0; ni < 4; ++ni)
#pragma unroll
            for (int q = 0; q < 4; ++q) {
                int r = row0 + wy * 64 + mi * 16 + quad * 4 + q;
                int c = n0 + wx * 64 + ni * 16 + lm;
                if (r < N) {
                    if (MODE == 1) Cb[(size_t)r * ldout + c] = f2bf(relu_nan(acc[mi][ni][q]));
                    else           Cf[(size_t)r * ldout + c] = acc[mi][ni][q];
                }
            }
}

extern "C" void kernel_launch(void* const* d_in, const int* in_sizes, int n_in,
                              void* d_out, int out_size, void* d_ws, size_t ws_size,
                              hipStream_t stream) {
    const float* X    = (const float*)d_in[0];
    const int* src    = (const int*)d_in[1];
    const int* dst    = (const int*)d_in[2];
    const float* Wn   = (const float*)d_in[3];
    const float* Asrc = (const float*)d_in[4];
    const float* Adst = (const float*)d_in[5];
    const float* W1   = (const float*)d_in[6];
    const float* b1   = (const float*)d_in[7];
    const float* W2   = (const float*)d_in[8];
    const float* b2   = (const float*)d_in[9];
    float* out = (float*)d_out;

    const int N = in_sizes[0] / 128;   // 50000
    const int E = in_sizes[1];         // 800000
    const int NBS = (N + 255) / 256;   // scan blocks
    const int NR = (N + 127) / 128;    // GEMM row tiles (MLP)
    const int NRH = (N + 255) / 256;   // gemmh row tiles

    // ws layout (16B-aligned offsets), ~70.3 MB.
    size_t off = 0;
    char* w = (char*)d_ws;
    unsigned short* aggb = (unsigned short*)(w + off); off += (size_t)N * 512 * 2;  // agg [N,4,128] bf16; reused as MLP hidden
    float* s_src = (float*)(w + off);                  off += (size_t)N * 4 * 4;
    float* s_dst = (float*)(w + off);                  off += (size_t)N * 4 * 4;
    float* invden= (float*)(w + off);                  off += (size_t)N * 4 * 4;
    int* cnt     = (int*)(w + off);                    off += (size_t)N * 4;
    int* rowptr  = (int*)(w + off);                    off += ((size_t)(N + 1) * 4 + 15) & ~15ull;
    int* wcnt    = (int*)(w + off);                    off += (size_t)N * 4;
    int* bsum    = (int*)(w + off);                    off += ((size_t)NBS * 4 + 15) & ~15ull;
    int* esrc    = (int*)(w + off);                    off += (size_t)E * 4;
    float* ex4   = (float*)(w + off);                  off += (size_t)E * 4 * 4;
    unsigned short* W1T = (unsigned short*)(w + off);  off += 256 * 256 * 2;
    unsigned short* W2T = (unsigned short*)(w + off);  off += 128 * 256 * 2;
    unsigned short* WnT = (unsigned short*)(w + off);  off += 256 * 128 * 2;
    float* Wsd   = (float*)(w + off);                  off += 8 * 128 * 4;
    const size_t required = off;

    if (ws_size < required) {
        k_fill<<<dim3((out_size + 255) / 256), dim3(256), 0, stream>>>(
            out, (float)(ws_size >> 20), out_size);
        return;
    }

    // d_out staging: Xb (bf16 [N,128]) -> gathered by k_agg;
    // then concat (bf16 [N,256]) from k_gemmh -> consumed by gemm1; then final fp32 out.
    unsigned short* Xb     = (unsigned short*)d_out;
    unsigned short* concat = (unsigned short*)d_out;
    unsigned short* hid    = aggb;   // agg dead after k_gemmh

    hipMemsetAsync(cnt, 0, (size_t)N * sizeof(int), stream);
    k_prep<<<dim3(2048), dim3(256), 0, stream>>>(X, Xb, Wn, WnT, W1, W1T, W2, W2T,
                                                 Asrc, Adst, Wsd, dst, cnt, N, E);
    k_scores<<<dim3((N * 8 + 255) / 256), dim3(256), 0, stream>>>(Xb, Wsd, s_src, s_dst, N);
    k_scan1<<<dim3(NBS), dim3(256), 0, stream>>>(cnt, rowptr, bsum, N);
    k_scan2<<<dim3(1), dim3(64), 0, stream>>>(bsum, NBS);
    k_scan3<<<dim3((N + 256) / 256), dim3(256), 0, stream>>>(rowptr, bsum, wcnt, N, E);
    k_scatter<<<dim3((E + 255) / 256), dim3(256), 0, stream>>>(src, dst, wcnt, s_src, s_dst,
                                                               esrc, ex4, E);
    k_agg<<<dim3((N + 3) / 4), dim3(256), 0, stream>>>(Xb, rowptr, esrc, ex4, aggb, invden, N);
    k_gemmh<<<dim3(NRH, 4), dim3(256), 0, stream>>>(aggb, WnT, invden, concat, N);
    // layer 1: hidden = relu(concat @ W1 + b1) -> hid (agg region, dead)
    k_gemm<256, 1><<<dim3(NR, 2), dim3(256), 0, stream>>>(
        concat, W1T, b1, hid, nullptr, N, 256);
    // layer 2: out = hidden @ W2 + b2 -> fp32 into d_out
    k_gemm<256, 2><<<dim3(NR, 1), dim3(256), 0, stream>>>(
        hid, W2T, b2, nullptr, out, N, 128);
}